// Round 6
// baseline (737.185 us; speedup 1.0000x reference)
//
#include <hip/hip_runtime.h>
#include <cstddef>
#include <cstdint>

// Problem constants (from reference): B=256, T=512, I=128, H=64, 4H=256.
#define NB 256
#define NT 512
#define H4 256

typedef float v2f __attribute__((ext_vector_type(2)));

// Quad-lane exchange via DPP quad_perm (pure VALU, no LDS pipe):
// xor1: perm(1,0,3,2)=0xB1 ; xor2: perm(2,3,0,1)=0x4E
__device__ __forceinline__ float dpp_xor1(float x) {
    int r = __builtin_amdgcn_update_dpp(0, __float_as_int(x), 0xB1, 0xF, 0xF, true);
    return __int_as_float(r);
}
__device__ __forceinline__ float dpp_xor2(float x) {
    int r = __builtin_amdgcn_update_dpp(0, __float_as_int(x), 0x4E, 0xF, 0xF, true);
    return __int_as_float(r);
}

// returns x[m] for runtime m (2-level cndmask)
__device__ __forceinline__ float sel4(float x0, float x1, float x2, float x3, int m) {
    float lo = (m & 1) ? x1 : x0;
    float hi = (m & 1) ? x3 : x2;
    return (m & 2) ? hi : lo;
}

// ---------------------------------------------------------------------------
// Transpose W [256, K] -> Wt [K, 256] (tiny, once; layer-0 GEMM only)
// ---------------------------------------------------------------------------
__global__ void transpose_w(const float* __restrict__ W, float* __restrict__ Wt, int K) {
    int idx = blockIdx.x * 256 + threadIdx.x;
    if (idx < 256 * K) {
        int n = idx / K, k = idx - n * K;
        Wt[k * 256 + n] = W[idx];
    }
}

// ---------------------------------------------------------------------------
// Input-projection GEMM for layer 0 only (K=128). Unchanged.
// ---------------------------------------------------------------------------
template <int K>
__global__ __launch_bounds__(256) void gemm_xp(
    const float* __restrict__ X, const float* __restrict__ Wt,
    const float* __restrict__ b1, const float* __restrict__ b2,
    float* __restrict__ XP)
{
    constexpr int TM = 64;
    constexpr int KC = 16;
    __shared__ __align__(16) float xT[K][TM + 4];
    __shared__ __align__(16) float wc[KC][256];
    const int m0 = blockIdx.x * TM;
    const int t  = threadIdx.x;
    const int cg = (t & 63) * 4;
    const int rg = (t >> 6) * 16;

    for (int idx = t; idx < TM * K; idx += 256) {
        int r = idx / K, k = idx - r * K;
        xT[k][r] = X[(size_t)(m0 + r) * K + k];
    }

    float acc[16][4];
    #pragma unroll
    for (int i = 0; i < 16; ++i)
        #pragma unroll
        for (int j = 0; j < 4; ++j) acc[i][j] = 0.f;

    for (int kc = 0; kc < K; kc += KC) {
        __syncthreads();
        #pragma unroll
        for (int i = 0; i < 4; ++i) {
            int e4 = (t + i * 256) * 4;
            int k = e4 >> 8, n = e4 & 255;
            *(float4*)&wc[k][n] = *(const float4*)&Wt[(size_t)(kc + k) * 256 + n];
        }
        __syncthreads();
        #pragma unroll
        for (int k = 0; k < KC; ++k) {
            float4 w = *(const float4*)&wc[k][cg];
            float xr[16];
            #pragma unroll
            for (int q = 0; q < 4; ++q)
                *(float4*)&xr[q * 4] = *(const float4*)&xT[kc + k][rg + q * 4];
            #pragma unroll
            for (int rr = 0; rr < 16; ++rr) {
                acc[rr][0] += xr[rr] * w.x;
                acc[rr][1] += xr[rr] * w.y;
                acc[rr][2] += xr[rr] * w.z;
                acc[rr][3] += xr[rr] * w.w;
            }
        }
    }

    float bias[4];
    #pragma unroll
    for (int j = 0; j < 4; ++j) bias[j] = b1[cg + j] + b2[cg + j];
    #pragma unroll
    for (int rr = 0; rr < 16; ++rr) {
        float4 o;
        o.x = acc[rr][0] + bias[0];
        o.y = acc[rr][1] + bias[1];
        o.z = acc[rr][2] + bias[2];
        o.w = acc[rr][3] + bias[3];
        *(float4*)&XP[(size_t)(m0 + rg + rr) * 256 + cg] = o;
    }
}

// ---------------------------------------------------------------------------
// Fused 3-layer wavefront-pipelined LSTM scan.
// One 768-thread block per batch element. Waves [4L, 4L+4) run layer L with
// the round-5 XOR quad scheme (ks = k-slice AND owned gate, u = unit).
// Layers 1,2 fuse their input projection: p[j] += W_ih[slot j] . h^{L-1}_t
// (second register matvec, +64 weights/lane). Pipeline: at step s layer L
// computes t = s-L; h handoff via per-layer double-buffered LDS hb[L][2][64].
// ONE raw s_barrier per step, lgkmcnt(0) only (no vmcnt drain) -> layer-0 xp
// prefetch (depth 4) stays in flight across barriers. 3 waves/SIMD hide each
// other's trans/LDS latency.
// ---------------------------------------------------------------------------
__global__ __launch_bounds__(768) void lstm_fused3(
    const float* __restrict__ xp,    // [B*T, 256] layer-0 xp (incl. both biases)
    const float* __restrict__ Whh0,
    const float* __restrict__ Wih1, const float* __restrict__ Whh1,
    const float* __restrict__ bi1, const float* __restrict__ bh1,
    const float* __restrict__ Wih2, const float* __restrict__ Whh2,
    const float* __restrict__ bi2, const float* __restrict__ bh2,
    float* __restrict__ hl)          // [B, 64] layer-2 h at t = NT-1
{
    const int tid = threadIdx.x;
    const int b = blockIdx.x;
    const int L = tid >> 8;            // 0,1,2 (4 waves each)
    const int t256 = tid & 255;
    const int ks = t256 & 3;
    const int u = t256 >> 2;           // 0..63

    __shared__ __align__(16) float hb[3][2][64];

    // Recurrent weights, XOR-permuted: slot j = gate (ks^j), k-slice ks
    const float* Whh = (L == 0) ? Whh0 : (L == 1) ? Whh1 : Whh2;
    v2f wg[4][8];
    #pragma unroll
    for (int j = 0; j < 4; ++j) {
        const v2f* Wv = (const v2f*)(Whh + (size_t)(((ks ^ j) * 64) + u) * 64 + ks * 16);
        #pragma unroll
        for (int q = 0; q < 8; ++q) wg[j][q] = Wv[q];
    }
    // Input-projection weights + bias for layers 1,2
    v2f wi[4][8];
    float bsum = 0.f;
    if (L > 0) {
        const float* Wih = (L == 1) ? Wih1 : Wih2;
        #pragma unroll
        for (int j = 0; j < 4; ++j) {
            const v2f* Wv = (const v2f*)(Wih + (size_t)(((ks ^ j) * 64) + u) * 64 + ks * 16);
            #pragma unroll
            for (int q = 0; q < 8; ++q) wi[j][q] = Wv[q];
        }
        const float* bi = (L == 1) ? bi1 : bi2;
        const float* bh = (L == 1) ? bh1 : bh2;
        bsum = bi[ks * 64 + u] + bh[ks * 64 + u];
    }

    // Per-lane activation constants (gate 2 = tanh)
    const float LOG2E = 1.4426950408889634f;
    const float M = (ks == 2) ? (2.f * LOG2E) : LOG2E;
    const float A = (ks == 2) ? 2.f : 1.f;
    const float Bc = (ks == 2) ? -1.f : 0.f;

    if (tid < 384) ((float*)hb)[tid] = 0.f;   // zero all h buffers

    // layer-0 xp prefetch ring (depth 4)
    const float* xpb = xp + (size_t)b * NT * H4 + (ks * 64 + u);
    float xr[4];
    if (L == 0) {
        #pragma unroll
        for (int d = 0; d < 4; ++d) xr[d] = xpb[(size_t)d * H4];
    }

    asm volatile("s_waitcnt lgkmcnt(0)" ::: "memory");
    __builtin_amdgcn_s_barrier();
    __builtin_amdgcn_sched_barrier(0);

    float c = 0.f, h = 0.f;
    const bool writer = (ks == 0);

    for (int s = 0; s < NT + 2; ++s) {
        const int t = s - L;
        const bool active = (t >= 0) && (t < NT);
        if (active) {
            // ---- own-h matvec over k-slice ks ----
            const v2f* hv = (const v2f*)&hb[L][t & 1][ks * 16];
            float p[4];
            {
                v2f h0 = hv[0], h1 = hv[1], h2 = hv[2], h3 = hv[3];
                v2f h4 = hv[4], h5 = hv[5], h6 = hv[6], h7 = hv[7];
                #pragma unroll
                for (int j = 0; j < 4; ++j) {
                    v2f s0 = wg[j][0] * h0 + wg[j][2] * h2;
                    v2f s1 = wg[j][1] * h1 + wg[j][3] * h3;
                    s0 += wg[j][4] * h4 + wg[j][6] * h6;
                    s1 += wg[j][5] * h5 + wg[j][7] * h7;
                    v2f ss = s0 + s1;
                    p[j] = ss.x + ss.y;
                }
            }
            float xc;
            if (L == 0) {
                xc = xr[t & 3];
                int tn = t + 4; if (tn > NT - 1) tn = NT - 1;
                xr[t & 3] = xpb[(size_t)tn * H4];     // fire-and-forget refill
            } else {
                // ---- fused input projection: h^{L-1}_t slice ----
                const v2f* gvp = (const v2f*)&hb[L - 1][(t + 1) & 1][ks * 16];
                v2f g0 = gvp[0], g1 = gvp[1], g2 = gvp[2], g3 = gvp[3];
                v2f g4 = gvp[4], g5 = gvp[5], g6 = gvp[6], g7 = gvp[7];
                #pragma unroll
                for (int j = 0; j < 4; ++j) {
                    v2f s0 = wi[j][0] * g0 + wi[j][2] * g2;
                    v2f s1 = wi[j][1] * g1 + wi[j][3] * g3;
                    s0 += wi[j][4] * g4 + wi[j][6] * g6;
                    s1 += wi[j][5] * g5 + wi[j][7] * g7;
                    v2f ss = s0 + s1;
                    p[j] += ss.x + ss.y;
                }
                xc = bsum;
            }

            // ---- reduce-scatter: full pre-activation of OWN gate ks ----
            float S = p[0] + dpp_xor1(p[1]);
            float t3 = dpp_xor2(dpp_xor1(p[3]));
            S += dpp_xor2(p[2]) + t3;
            float pre = S + xc;

            // ---- single branchless activation chain ----
            float e = __builtin_amdgcn_exp2f(-(pre * M));
            float y = __builtin_amdgcn_rcpf(1.f + e);
            float act = __builtin_fmaf(A, y, Bc);

            // ---- allgather + gate extraction ----
            float a1 = dpp_xor1(act);
            float a2 = dpp_xor2(act);
            float a3 = dpp_xor2(a1);
            float ig = (ks & 1) ? (a1 * a3) : (act * a2);   // i*g
            float fv = sel4(a1, act, a3, a2, ks);           // f
            float ov = sel4(a3, a2, a1, act, ks);           // o

            // ---- cell update (redundant x4, identical bits) ----
            c = __builtin_fmaf(fv, c, ig);
            float e2 = __builtin_amdgcn_exp2f(-(c * (2.f * LOG2E)));
            float y2 = __builtin_amdgcn_rcpf(1.f + e2);
            float th = __builtin_fmaf(2.f, y2, -1.f);
            h = ov * th;

            if (writer) {
                hb[L][(t + 1) & 1][u] = h;       // parity no reader touches this step
                if (L == 2 && t == NT - 1) hl[(size_t)b * 64 + u] = h;
            }
        }
        asm volatile("s_waitcnt lgkmcnt(0)" ::: "memory");
        __builtin_amdgcn_s_barrier();
        __builtin_amdgcn_sched_barrier(0);
    }
}

// ---------------------------------------------------------------------------
// Final linear: out[b][o] = b_out[o] + sum_j h_last[b][j] * W_out[o][j]
// ---------------------------------------------------------------------------
__global__ __launch_bounds__(256) void final_linear(
    const float* __restrict__ hl,    // [256, 64]
    const float* __restrict__ Wout,  // [2, 64]
    const float* __restrict__ bout,  // [2]
    float* __restrict__ out)         // [256, 2]
{
    __shared__ float w[128];
    int t = threadIdx.x;
    if (t < 128) w[t] = Wout[t];
    __syncthreads();
    const float* h = hl + (size_t)t * 64;
    float a0 = bout[0], a1 = bout[1];
    #pragma unroll 8
    for (int j = 0; j < 64; ++j) {
        float hv = h[j];
        a0 += hv * w[j];
        a1 += hv * w[64 + j];
    }
    out[t * 2 + 0] = a0;
    out[t * 2 + 1] = a1;
}

// ---------------------------------------------------------------------------
extern "C" void kernel_launch(void* const* d_in, const int* in_sizes, int n_in,
                              void* d_out, int out_size, void* d_ws, size_t ws_size,
                              hipStream_t stream)
{
    const float* x     = (const float*)d_in[0];
    const float* W_ih0 = (const float*)d_in[1];
    const float* W_hh0 = (const float*)d_in[2];
    const float* b_ih0 = (const float*)d_in[3];
    const float* b_hh0 = (const float*)d_in[4];
    const float* W_ih1 = (const float*)d_in[5];
    const float* W_hh1 = (const float*)d_in[6];
    const float* b_ih1 = (const float*)d_in[7];
    const float* b_hh1 = (const float*)d_in[8];
    const float* W_ih2 = (const float*)d_in[9];
    const float* W_hh2 = (const float*)d_in[10];
    const float* b_ih2 = (const float*)d_in[11];
    const float* b_hh2 = (const float*)d_in[12];
    const float* W_out = (const float*)d_in[13];
    const float* b_out = (const float*)d_in[14];
    float* out = (float*)d_out;

    const size_t M = (size_t)NB * NT;                  // 131072
    const size_t XP_BYTES  = M * H4 * sizeof(float);   // 128 MiB
    const size_t WT0_BYTES = 128 * 256 * sizeof(float);
    const size_t HL_BYTES  = NB * 64 * sizeof(float);
    if (ws_size < XP_BYTES + WT0_BYTES + HL_BYTES)
        return;

    char* ws = (char*)d_ws;
    float* XP  = (float*)ws;
    float* WT0 = (float*)(ws + XP_BYTES);
    float* HL  = WT0 + 128 * 256;

    // Layer-0 input projection (parallel GEMM) — layers 1,2 are fused.
    transpose_w<<<128, 256, 0, stream>>>(W_ih0, WT0, 128);
    gemm_xp<128><<<(int)(M / 64), 256, 0, stream>>>(x, WT0, b_ih0, b_hh0, XP);

    // Fused 3-layer pipelined scan.
    lstm_fused3<<<NB, 768, 0, stream>>>(XP, W_hh0,
                                        W_ih1, W_hh1, b_ih1, b_hh1,
                                        W_ih2, W_hh2, b_ih2, b_hh2, HL);

    // Final projection.
    final_linear<<<1, 256, 0, stream>>>(HL, W_out, b_out, out);
}